// Round 2
// baseline (5997.819 us; speedup 1.0000x reference)
//
#include <hip/hip_runtime.h>
#include <stdint.h>
#include <stddef.h>

typedef unsigned short bf16;

__device__ __forceinline__ float bf2f(unsigned short u){
  union { uint32_t i; float f; } x; x.i = ((uint32_t)u) << 16; return x.f;
}
__device__ __forceinline__ unsigned short f2bf(float f){
  union { float f; uint32_t i; } x; x.f = f;
  uint32_t r = x.i + 0x7FFFu + ((x.i >> 16) & 1u);  // round-nearest-even
  return (unsigned short)(r >> 16);
}

// ---------------- threefry2x32 (bit-exact vs jax) ----------------
__host__ __device__ __forceinline__ uint32_t rotl32_(uint32_t x, int d){
  return (x << d) | (x >> (32 - d));
}
__host__ __device__ inline void tf2x32(uint32_t k0, uint32_t k1, uint32_t x0, uint32_t x1,
                                       uint32_t* o0, uint32_t* o1){
  uint32_t k2 = k0 ^ k1 ^ 0x1BD11BDAu;
#define TF_R4(ra,rb,rc,rd) \
  x0 += x1; x1 = rotl32_(x1,ra); x1 ^= x0; \
  x0 += x1; x1 = rotl32_(x1,rb); x1 ^= x0; \
  x0 += x1; x1 = rotl32_(x1,rc); x1 ^= x0; \
  x0 += x1; x1 = rotl32_(x1,rd); x1 ^= x0;
  x0 += k0; x1 += k1;
  TF_R4(13,15,26,6)  x0 += k1; x1 += k2 + 1u;
  TF_R4(17,29,16,24) x0 += k2; x1 += k0 + 2u;
  TF_R4(13,15,26,6)  x0 += k0; x1 += k1 + 3u;
  TF_R4(17,29,16,24) x0 += k1; x1 += k2 + 4u;
  TF_R4(13,15,26,6)  x0 += k2; x1 += k0 + 5u;
  *o0 = x0; *o1 = x1;
#undef TF_R4
}

// ---------------- small utils ----------------
__global__ void k_zeroi(int* __restrict__ p, int n){
  int i = blockIdx.x * 256 + threadIdx.x;
  if (i < n) p[i] = 0;
}

__global__ void k_f2bf(const float* __restrict__ in, bf16* __restrict__ out, int n4){
  int i = blockIdx.x * 256 + threadIdx.x;
  if (i < n4){
    float4 v = ((const float4*)in)[i];
    ushort4 u; u.x = f2bf(v.x); u.y = f2bf(v.y); u.z = f2bf(v.z); u.w = f2bf(v.w);
    ((ushort4*)out)[i] = u;
  }
}

// ---------------- CSR build ----------------
__global__ void k_deg(const int* __restrict__ dst, int* __restrict__ deg, int E){
  int i = blockIdx.x * 256 + threadIdx.x;
  if (i < E) atomicAdd(&deg[dst[i]], 1);
}

__global__ __launch_bounds__(256)
void k_scan_partial(const int* __restrict__ in, int* __restrict__ exc,
                    int* __restrict__ bsum, int n){
  __shared__ int tmp[256];
  int t = threadIdx.x, i = blockIdx.x * 256 + t;
  int v = (i < n) ? in[i] : 0;
  tmp[t] = v; __syncthreads();
  #pragma unroll
  for (int off = 1; off < 256; off <<= 1){
    int u = (t >= off) ? tmp[t - off] : 0; __syncthreads();
    tmp[t] += u; __syncthreads();
  }
  if (i < n) exc[i] = tmp[t] - v;
  if (t == 255) bsum[blockIdx.x] = tmp[255];
}

__global__ __launch_bounds__(1024)
void k_scan_bsum(int* __restrict__ bsum, int nb, int* __restrict__ total_out){
  __shared__ int tmp[1024];
  int t = threadIdx.x;
  int v = (t < nb) ? bsum[t] : 0;
  tmp[t] = v; __syncthreads();
  #pragma unroll
  for (int off = 1; off < 1024; off <<= 1){
    int u = (t >= off) ? tmp[t - off] : 0; __syncthreads();
    tmp[t] += u; __syncthreads();
  }
  if (t < nb) bsum[t] = tmp[t] - v;
  if (t == 1023) *total_out = tmp[1023];
}

__global__ void k_scan_add(int* __restrict__ exc, const int* __restrict__ bsum, int n){
  int i = blockIdx.x * 256 + threadIdx.x;
  if (i < n) exc[i] += bsum[blockIdx.x];
}

__global__ void k_fill(const int* __restrict__ src, const int* __restrict__ dst,
                       const int* __restrict__ rs, int* __restrict__ cur,
                       int* __restrict__ cs, int E){
  int i = blockIdx.x * 256 + threadIdx.x;
  if (i < E){
    int d = dst[i];
    int p = atomicAdd(&cur[d], 1);
    cs[rs[d] + p] = src[i];
  }
}

// ---------------- layer-1 mean aggregation (D=128 bf16), 1 wave per node ----------------
__global__ __launch_bounds__(64)
void k_agg128(const bf16* __restrict__ X, const int* __restrict__ rs,
              const int* __restrict__ cs, bf16* __restrict__ out){
  int node = blockIdx.x, lane = threadIdx.x;
  int s0 = rs[node], s1 = rs[node + 1];
  float ax = 0.f, ay = 0.f;
  for (int e = s0; e < s1; ++e){
    uint32_t v = ((const uint32_t*)(X + (size_t)cs[e] * 128))[lane];
    ax += bf2f((unsigned short)(v & 0xffffu));
    ay += bf2f((unsigned short)(v >> 16));
  }
  float inv = 1.f / fmaxf((float)(s1 - s0), 1.f);
  uint32_t o = (uint32_t)f2bf(ax * inv) | ((uint32_t)f2bf(ay * inv) << 16);
  ((uint32_t*)(out + (size_t)node * 128))[lane] = o;
}

// ---------------- combined weights (Wr[1]+Wr[2], b[1]+b[2]) ----------------
__global__ void k_combine(const float* __restrict__ Wr1, const float* __restrict__ b1,
                          const float* __restrict__ Wr2, const float* __restrict__ b2,
                          float* __restrict__ wc1, float* __restrict__ bc1,
                          float* __restrict__ wc2, float* __restrict__ bc2, int g, int O){
  int i = blockIdx.x * 256 + threadIdx.x;
  const int W1 = 128 * 256;
  const int W2 = 256 * O;
  if (i < W1){
    wc1[i] = Wr1[(size_t)(3*g+1)*W1 + i] + Wr1[(size_t)(3*g+2)*W1 + i];
  } else if (i < W1 + 256){
    int j = i - W1;
    bc1[j] = b1[(3*g+1)*256 + j] + b1[(3*g+2)*256 + j];
  } else if (i < W1 + 256 + W2){
    int j = i - W1 - 256;
    wc2[j] = Wr2[W2 + j] + Wr2[2*W2 + j];
  } else if (i < W1 + 256 + W2 + O){
    int j = i - W1 - 256 - W2;
    bc2[j] = b2[O + j] + b2[2*O + j];
  }
}

// ---------------- tiled GEMM: C[M,N] = sum_seg A_s[M,K](bf16) @ B_s[K,N](f32) (+bias) ----------------
__device__ __forceinline__ float4 load4a(const bf16* p){
  ushort4 u = *(const ushort4*)p;
  return make_float4(bf2f(u.x), bf2f(u.y), bf2f(u.z), bf2f(u.w));
}
__device__ __forceinline__ void store1c(float* p, float v){ *p = v; }
__device__ __forceinline__ void store1c(bf16* p, float v){ *p = f2bf(v); }

template<int NSEG, typename TC>
__global__ __launch_bounds__(256)
void k_gemm(const bf16* __restrict__ A0, const float* __restrict__ B0,
            const bf16* __restrict__ A1, const float* __restrict__ B1,
            const bf16* __restrict__ A2, const float* __restrict__ B2,
            const float* __restrict__ bias, TC* __restrict__ C,
            int M, int N, int K){
  __shared__ float As[16][64];   // As[k][m]
  __shared__ float Bs[16][64];   // Bs[k][n]
  const int tid = threadIdx.x;
  const int tx = tid & 15, ty = tid >> 4;
  const int r0 = blockIdx.y * 64, c0 = blockIdx.x * 64;
  float acc[4][4];
  #pragma unroll
  for (int i = 0; i < 4; ++i)
    #pragma unroll
    for (int j = 0; j < 4; ++j) acc[i][j] = 0.f;

  const int am = tid >> 2, ak = (tid & 3) * 4;   // A-tile load coords
  const int bk = tid >> 4, bn = (tid & 15) * 4;  // B-tile load coords
  const bool n4ok = ((N & 3) == 0);

  #pragma unroll
  for (int seg = 0; seg < NSEG; ++seg){
    const bf16* A = (seg == 0) ? A0 : ((seg == 1) ? A1 : A2);
    const float* B = (seg == 0) ? B0 : ((seg == 1) ? B1 : B2);
    for (int kk = 0; kk < K; kk += 16){
      float4 av = make_float4(0.f, 0.f, 0.f, 0.f);
      int arow = r0 + am;
      if (arow < M) av = load4a(A + (size_t)arow * K + kk + ak);
      float bv[4];
      if (n4ok && (c0 + bn + 3) < N){
        float4 b4 = *(const float4*)(B + (size_t)(kk + bk) * N + c0 + bn);
        bv[0] = b4.x; bv[1] = b4.y; bv[2] = b4.z; bv[3] = b4.w;
      } else {
        #pragma unroll
        for (int j = 0; j < 4; ++j){
          int n = c0 + bn + j;
          bv[j] = (n < N) ? B[(size_t)(kk + bk) * N + n] : 0.f;
        }
      }
      __syncthreads();
      As[ak+0][am] = av.x; As[ak+1][am] = av.y; As[ak+2][am] = av.z; As[ak+3][am] = av.w;
      *(float4*)&Bs[bk][bn] = make_float4(bv[0], bv[1], bv[2], bv[3]);
      __syncthreads();
      #pragma unroll
      for (int k = 0; k < 16; ++k){
        const float4 a4 = *(const float4*)&As[k][ty*4];
        const float4 b4 = *(const float4*)&Bs[k][tx*4];
        const float avv[4] = {a4.x, a4.y, a4.z, a4.w};
        const float bvv[4] = {b4.x, b4.y, b4.z, b4.w};
        #pragma unroll
        for (int i = 0; i < 4; ++i)
          #pragma unroll
          for (int j = 0; j < 4; ++j)
            acc[i][j] = fmaf(avv[i], bvv[j], acc[i][j]);
      }
    }
  }
  #pragma unroll
  for (int i = 0; i < 4; ++i){
    int row = r0 + ty*4 + i;
    if (row < M){
      #pragma unroll
      for (int j = 0; j < 4; ++j){
        int col = c0 + tx*4 + j;
        if (col < N){
          float v = acc[i][j];
          if (bias) v += bias[col];
          store1c(&C[(size_t)row * N + col], v);
        }
      }
    }
  }
}

// ---------------- fused relu + jax-exact dropout(0.5), in-place on bf16 ----------------
__global__ void k_relu_drop(bf16* __restrict__ h, int n, uint32_t k0, uint32_t k1){
  int i = blockIdx.x * 256 + threadIdx.x;
  if (i >= n) return;
  uint32_t o0, o1;
  tf2x32(k0, k1, 0u, (uint32_t)i, &o0, &o1);   // partitionable: counter = (0, i)
  uint32_t bits = o0 ^ o1;                      // 32-bit random bits
  float a = fmaxf(bf2f(h[i]), 0.f);
  h[i] = (bits >> 31) ? (bf16)0 : f2bf(a + a);  // keep iff u<0.5 iff MSB==0; scale 1/0.5
}

// ---------------- final assembly: mean-gather + residual + log_softmax ----------------
__global__ __launch_bounds__(128)
void k_assemble_t(const bf16* __restrict__ za0, const int* __restrict__ rs,
                  const int* __restrict__ cs, float* __restrict__ out, int O){
  int node = blockIdx.x, t = threadIdx.x;
  bool p0 = t < O, p1 = (t + 128) < O;
  int s0 = rs[node], s1 = rs[node + 1];
  float a0 = 0.f, a1 = 0.f;
  for (int e = s0; e < s1; ++e){
    const bf16* row = za0 + (size_t)cs[e] * O;
    if (p0) a0 += bf2f(row[t]);
    if (p1) a1 += bf2f(row[t + 128]);
  }
  float inv = 1.f / fmaxf((float)(s1 - s0), 1.f);
  float* orow = out + (size_t)node * O;
  float v0 = p0 ? (orow[t] + a0 * inv) : -3.4e38f;
  float v1 = p1 ? (orow[t + 128] + a1 * inv) : -3.4e38f;
  __shared__ float red[128];
  red[t] = fmaxf(v0, v1); __syncthreads();
  #pragma unroll
  for (int off = 64; off; off >>= 1){ if (t < off) red[t] = fmaxf(red[t], red[t+off]); __syncthreads(); }
  float mx = red[0]; __syncthreads();
  float es = (p0 ? expf(v0 - mx) : 0.f) + (p1 ? expf(v1 - mx) : 0.f);
  red[t] = es; __syncthreads();
  #pragma unroll
  for (int off = 64; off; off >>= 1){ if (t < off) red[t] += red[t+off]; __syncthreads(); }
  float lse = mx + logf(red[0]);
  if (p0) orow[t] = v0 - lse;
  if (p1) orow[t + 128] = v1 - lse;
}

__global__ __launch_bounds__(128)
void k_assemble_a(const bf16* __restrict__ zt1, const bf16* __restrict__ za2,
                  const int* __restrict__ rs_ta, const int* __restrict__ cs_ta,
                  const int* __restrict__ rs_aa, const int* __restrict__ cs_aa,
                  float* __restrict__ out, int O){
  int node = blockIdx.x, t = threadIdx.x;
  bool p0 = t < O, p1 = (t + 128) < O;
  float ta0 = 0.f, ta1 = 0.f, aa0 = 0.f, aa1 = 0.f;
  int s0 = rs_ta[node], s1 = rs_ta[node + 1];
  for (int e = s0; e < s1; ++e){
    const bf16* row = zt1 + (size_t)cs_ta[e] * O;
    if (p0) ta0 += bf2f(row[t]);
    if (p1) ta1 += bf2f(row[t + 128]);
  }
  float invta = 1.f / fmaxf((float)(s1 - s0), 1.f);
  s0 = rs_aa[node]; s1 = rs_aa[node + 1];
  for (int e = s0; e < s1; ++e){
    const bf16* row = za2 + (size_t)cs_aa[e] * O;
    if (p0) aa0 += bf2f(row[t]);
    if (p1) aa1 += bf2f(row[t + 128]);
  }
  float invaa = 1.f / fmaxf((float)(s1 - s0), 1.f);
  float* orow = out + (size_t)node * O;
  float v0 = p0 ? (orow[t] + ta0 * invta + aa0 * invaa) : -3.4e38f;
  float v1 = p1 ? (orow[t + 128] + ta1 * invta + aa1 * invaa) : -3.4e38f;
  __shared__ float red[128];
  red[t] = fmaxf(v0, v1); __syncthreads();
  #pragma unroll
  for (int off = 64; off; off >>= 1){ if (t < off) red[t] = fmaxf(red[t], red[t+off]); __syncthreads(); }
  float mx = red[0]; __syncthreads();
  float es = (p0 ? expf(v0 - mx) : 0.f) + (p1 ? expf(v1 - mx) : 0.f);
  red[t] = es; __syncthreads();
  #pragma unroll
  for (int off = 64; off; off >>= 1){ if (t < off) red[t] += red[t+off]; __syncthreads(); }
  float lse = mx + logf(red[0]);
  if (p0) orow[t] = v0 - lse;
  if (p1) orow[t + 128] = v1 - lse;
}

// ---------------- host ----------------
template<typename TC>
static void launch_gemm(int nseg,
                        const bf16* A0, const float* B0,
                        const bf16* A1, const float* B1,
                        const bf16* A2, const float* B2,
                        const float* bias, TC* C,
                        int M, int N, int K, hipStream_t s){
  dim3 grid((N + 63) / 64, (M + 63) / 64), blk(256);
  if (nseg == 1)      k_gemm<1, TC><<<grid, blk, 0, s>>>(A0,B0,A1,B1,A2,B2,bias,C,M,N,K);
  else if (nseg == 2) k_gemm<2, TC><<<grid, blk, 0, s>>>(A0,B0,A1,B1,A2,B2,bias,C,M,N,K);
  else                k_gemm<3, TC><<<grid, blk, 0, s>>>(A0,B0,A1,B1,A2,B2,bias,C,M,N,K);
}

extern "C" void kernel_launch(void* const* d_in, const int* in_sizes, int n_in,
                              void* d_out, int out_size, void* d_ws, size_t ws_size,
                              hipStream_t stream){
  (void)n_in; (void)out_size; (void)ws_size;
  const float* xa  = (const float*)d_in[0];
  const float* xt  = (const float*)d_in[1];
  const int*   e_at = (const int*)d_in[2];
  const int*   e_ta = (const int*)d_in[3];
  const int*   e_aa = (const int*)d_in[4];
  const float* Wl1 = (const float*)d_in[5];
  const float* Wr1 = (const float*)d_in[6];
  const float* b1  = (const float*)d_in[7];
  const float* Wl2_[3] = {(const float*)d_in[8],  (const float*)d_in[11], (const float*)d_in[14]};
  const float* Wr2_[3] = {(const float*)d_in[9],  (const float*)d_in[12], (const float*)d_in[15]};
  const float* b2_[3]  = {(const float*)d_in[10], (const float*)d_in[13], (const float*)d_in[16]};

  const int NA = in_sizes[0] / 128;
  const int NT = in_sizes[1] / 128;
  const int EAT = in_sizes[2] / 2, ETA = in_sizes[3] / 2, EAA = in_sizes[4] / 2;
  const int Ov[3] = {129, 32, 18};

  // -------- workspace layout (~285 MB) --------
  char* Wp = (char*)d_ws;
  size_t off = 0;
  auto alloc = [&](size_t bytes)->char*{
    char* p = Wp + off; off = (off + bytes + 255) & ~(size_t)255; return p;
  };
  bf16* xa_b = (bf16*)alloc((size_t)NA * 128 * 2);
  bf16* xt_b = (bf16*)alloc((size_t)NT * 128 * 2);
  bf16* m_at = (bf16*)alloc((size_t)NT * 128 * 2);
  bf16* m_ta = (bf16*)alloc((size_t)NA * 128 * 2);
  bf16* m_aa = (bf16*)alloc((size_t)NA * 128 * 2);
  bf16* h_a  = (bf16*)alloc((size_t)NA * 256 * 2);
  bf16* h_t  = (bf16*)alloc((size_t)NT * 256 * 2);
  bf16* za0  = (bf16*)alloc((size_t)NA * 129 * 2);
  bf16* zt1  = (bf16*)alloc((size_t)NT * 129 * 2);
  bf16* za2  = (bf16*)alloc((size_t)NA * 129 * 2);
  float* wc1 = (float*)alloc(128 * 256 * 4);
  float* bc1 = (float*)alloc(256 * 4);
  float* wc2 = (float*)alloc(256 * 129 * 4);
  float* bc2 = (float*)alloc(129 * 4);
  int* rs_at  = (int*)alloc((size_t)(NT + 1) * 4);
  int* rs_ta  = (int*)alloc((size_t)(NA + 1) * 4);
  int* rs_aa  = (int*)alloc((size_t)(NA + 1) * 4);
  int* cur_at = (int*)alloc((size_t)NT * 4);
  int* cur_ta = (int*)alloc((size_t)NA * 4);
  int* cur_aa = (int*)alloc((size_t)NA * 4);
  int* bsum   = (int*)alloc(2048 * 4);
  int* cs_at  = (int*)alloc((size_t)EAT * 4);
  int* cs_ta  = (int*)alloc((size_t)ETA * 4);
  int* cs_aa  = (int*)alloc((size_t)EAA * 4);

  // -------- bf16 copies of inputs --------
  k_f2bf<<<(NA * 128 / 4 + 255) / 256, 256, 0, stream>>>(xa, xa_b, NA * 128 / 4);
  k_f2bf<<<(NT * 128 / 4 + 255) / 256, 256, 0, stream>>>(xt, xt_b, NT * 128 / 4);

  // -------- CSR build (per relation, shared by all 3 GNNs) --------
  auto build_csr = [&](const int* edges, int E, int n, int* rs, int* cur, int* cs){
    int ebl = (E + 255) / 256, nbl = (n + 255) / 256;
    k_zeroi<<<nbl, 256, 0, stream>>>(cur, n);
    k_deg<<<ebl, 256, 0, stream>>>(edges + E, cur, E);
    k_scan_partial<<<nbl, 256, 0, stream>>>(cur, rs, bsum, n);
    k_scan_bsum<<<1, 1024, 0, stream>>>(bsum, nbl, rs + n);
    k_scan_add<<<nbl, 256, 0, stream>>>(rs, bsum, n);
    k_zeroi<<<nbl, 256, 0, stream>>>(cur, n);
    k_fill<<<ebl, 256, 0, stream>>>(edges, edges + E, rs, cur, cs, E);
  };
  build_csr(e_at, EAT, NT, rs_at, cur_at, cs_at);
  build_csr(e_ta, ETA, NA, rs_ta, cur_ta, cs_ta);
  build_csr(e_aa, EAA, NA, rs_aa, cur_aa, cs_aa);

  // -------- layer-1 mean aggregations (g-invariant, compute once) --------
  k_agg128<<<NT, 64, 0, stream>>>(xa_b, rs_at, cs_at, m_at);
  k_agg128<<<NA, 64, 0, stream>>>(xt_b, rs_ta, cs_ta, m_ta);
  k_agg128<<<NA, 64, 0, stream>>>(xa_b, rs_aa, cs_aa, m_aa);

  size_t outOff = 0;
  for (int g = 0; g < 3; ++g){
    const int O = Ov[g];
    float* outA = (float*)d_out + outOff;
    float* outT = outA + (size_t)NA * O;
    outOff += (size_t)(NA + NT) * O;

    const float* Wl1g = Wl1 + (size_t)(3 * g) * 128 * 256;
    const float* Wr1g = Wr1 + (size_t)(3 * g) * 128 * 256;
    const float* b1g  = b1  + (size_t)(3 * g) * 256;
    const float* Wl2g = Wl2_[g];
    const float* Wr2g = Wr2_[g];
    const float* b2g  = b2_[g];

    // combined right/self weights: Wr1[g,1]+Wr1[g,2], Wr2[1]+Wr2[2] (+bias sums)
    int tot = 128 * 256 + 256 + 256 * O + O;
    k_combine<<<(tot + 255) / 256, 256, 0, stream>>>(Wr1, b1, Wr2g, b2g,
                                                     wc1, bc1, wc2, bc2, g, O);

    // layer 1: h_a = m_ta@Wl1[g,1] + m_aa@Wl1[g,2] + xa@(Wr1[g,1]+Wr1[g,2]) + (b1[g,1]+b1[g,2])
    launch_gemm<bf16>(3, m_ta, Wl1g + 1 * 128 * 256,
                         m_aa, Wl1g + 2 * 128 * 256,
                         xa_b, wc1,
                         bc1, h_a, NA, 256, 128, stream);
    // h_t = m_at@Wl1[g,0] + xt@Wr1[g,0] + b1[g,0]
    launch_gemm<bf16>(2, m_at, Wl1g, xt_b, Wr1g, nullptr, nullptr,
                      b1g, h_t, NT, 256, 128, stream);

    // dropout keys: key_g = tf((0,42),(0,g)); foldlike split -> k_a=(0,0), k_t=(0,1)
    uint32_t kg0, kg1, ka0, ka1, kt0, kt1;
    tf2x32(0u, 42u, 0u, (uint32_t)g, &kg0, &kg1);
    tf2x32(kg0, kg1, 0u, 0u, &ka0, &ka1);
    tf2x32(kg0, kg1, 0u, 1u, &kt0, &kt1);
    k_relu_drop<<<(NA * 256 + 255) / 256, 256, 0, stream>>>(h_a, NA * 256, ka0, ka1);
    k_relu_drop<<<(NT * 256 + 255) / 256, 256, 0, stream>>>(h_t, NT * 256, kt0, kt1);

    // layer 2: transform-then-aggregate (linearity of seg_mean)
    launch_gemm<bf16>(1, h_a, Wl2g + 0 * 256 * O, nullptr,nullptr,nullptr,nullptr,
                      nullptr, za0, NA, O, 256, stream);
    launch_gemm<bf16>(1, h_t, Wl2g + 1 * 256 * O, nullptr,nullptr,nullptr,nullptr,
                      nullptr, zt1, NT, O, 256, stream);
    launch_gemm<bf16>(1, h_a, Wl2g + 2 * 256 * O, nullptr,nullptr,nullptr,nullptr,
                      nullptr, za2, NA, O, 256, stream);
    // residual/self terms straight into d_out
    launch_gemm<float>(1, h_a, wc2, nullptr,nullptr,nullptr,nullptr,
                       bc2, outA, NA, O, 256, stream);
    launch_gemm<float>(1, h_t, Wr2g + 0 * 256 * O, nullptr,nullptr,nullptr,nullptr,
                       b2g, outT, NT, O, 256, stream);

    // gather means + log_softmax
    k_assemble_t<<<NT, 128, 0, stream>>>(za0, rs_at, cs_at, outT, O);
    k_assemble_a<<<NA, 128, 0, stream>>>(zt1, za2, rs_ta, cs_ta, rs_aa, cs_aa, outA, O);
  }
}

// Round 3
// 2709.536 us; speedup vs baseline: 2.2136x; 2.2136x over previous
//
#include <hip/hip_runtime.h>
#include <stdint.h>
#include <stddef.h>

typedef unsigned short bf16;
typedef __attribute__((ext_vector_type(8))) short short8;   // 8 bf16 = 4 VGPRs (MFMA A/B frag)
typedef __attribute__((ext_vector_type(4))) float f32x4;    // MFMA C/D frag

__device__ __forceinline__ float bf2f(unsigned short u){
  union { uint32_t i; float f; } x; x.i = ((uint32_t)u) << 16; return x.f;
}
__device__ __forceinline__ unsigned short f2bf(float f){
  union { float f; uint32_t i; } x; x.f = f;
  uint32_t r = x.i + 0x7FFFu + ((x.i >> 16) & 1u);  // RNE
  return (unsigned short)(r >> 16);
}
__device__ __forceinline__ uint32_t pk2(float a, float b){
  return (uint32_t)f2bf(a) | ((uint32_t)f2bf(b) << 16);
}

// ---------------- threefry2x32 (bit-exact vs jax partitionable) ----------------
__host__ __device__ __forceinline__ uint32_t rotl32_(uint32_t x, int d){
  return (x << d) | (x >> (32 - d));
}
__host__ __device__ inline void tf2x32(uint32_t k0, uint32_t k1, uint32_t x0, uint32_t x1,
                                       uint32_t* o0, uint32_t* o1){
  uint32_t k2 = k0 ^ k1 ^ 0x1BD11BDAu;
#define TF_R4(ra,rb,rc,rd) \
  x0 += x1; x1 = rotl32_(x1,ra); x1 ^= x0; \
  x0 += x1; x1 = rotl32_(x1,rb); x1 ^= x0; \
  x0 += x1; x1 = rotl32_(x1,rc); x1 ^= x0; \
  x0 += x1; x1 = rotl32_(x1,rd); x1 ^= x0;
  x0 += k0; x1 += k1;
  TF_R4(13,15,26,6)  x0 += k1; x1 += k2 + 1u;
  TF_R4(17,29,16,24) x0 += k2; x1 += k0 + 2u;
  TF_R4(13,15,26,6)  x0 += k0; x1 += k1 + 3u;
  TF_R4(17,29,16,24) x0 += k1; x1 += k2 + 4u;
  TF_R4(13,15,26,6)  x0 += k2; x1 += k0 + 5u;
  *o0 = x0; *o1 = x1;
#undef TF_R4
}

// ---------------- small utils ----------------
__global__ void k_zeroi(int* __restrict__ p, int n){
  int i = blockIdx.x * 256 + threadIdx.x;
  if (i < n) p[i] = 0;
}

__global__ void k_f2bf(const float* __restrict__ in, bf16* __restrict__ out, int n4){
  int i = blockIdx.x * 256 + threadIdx.x;
  if (i < n4){
    float4 v = ((const float4*)in)[i];
    ushort4 u; u.x = f2bf(v.x); u.y = f2bf(v.y); u.z = f2bf(v.z); u.w = f2bf(v.w);
    ((ushort4*)out)[i] = u;
  }
}

// ---------------- CSR build ----------------
__global__ void k_deg(const int* __restrict__ dst, int* __restrict__ deg, int E){
  int i = blockIdx.x * 256 + threadIdx.x;
  if (i < E) atomicAdd(&deg[dst[i]], 1);
}

__global__ __launch_bounds__(256)
void k_scan_partial(const int* __restrict__ in, int* __restrict__ exc,
                    int* __restrict__ bsum, int n){
  __shared__ int tmp[256];
  int t = threadIdx.x, i = blockIdx.x * 256 + t;
  int v = (i < n) ? in[i] : 0;
  tmp[t] = v; __syncthreads();
  #pragma unroll
  for (int off = 1; off < 256; off <<= 1){
    int u = (t >= off) ? tmp[t - off] : 0; __syncthreads();
    tmp[t] += u; __syncthreads();
  }
  if (i < n) exc[i] = tmp[t] - v;
  if (t == 255) bsum[blockIdx.x] = tmp[255];
}

__global__ __launch_bounds__(1024)
void k_scan_bsum(int* __restrict__ bsum, int nb, int* __restrict__ total_out){
  __shared__ int tmp[1024];
  int t = threadIdx.x;
  int v = (t < nb) ? bsum[t] : 0;
  tmp[t] = v; __syncthreads();
  #pragma unroll
  for (int off = 1; off < 1024; off <<= 1){
    int u = (t >= off) ? tmp[t - off] : 0; __syncthreads();
    tmp[t] += u; __syncthreads();
  }
  if (t < nb) bsum[t] = tmp[t] - v;
  if (t == 1023) *total_out = tmp[1023];
}

__global__ void k_scan_add(int* __restrict__ exc, const int* __restrict__ bsum, int n){
  int i = blockIdx.x * 256 + threadIdx.x;
  if (i < n) exc[i] += bsum[blockIdx.x];
}

__global__ void k_fill(const int* __restrict__ src, const int* __restrict__ dst,
                       const int* __restrict__ rs, int* __restrict__ cur,
                       int* __restrict__ cs, int E){
  int i = blockIdx.x * 256 + threadIdx.x;
  if (i < E){
    int d = dst[i];
    int p = atomicAdd(&cur[d], 1);
    cs[rs[d] + p] = src[i];
  }
}

// ---------------- layer-1 mean aggregation (D=128), 1 wave/node, unroll-4 ----------------
__global__ __launch_bounds__(64)
void k_agg128f(const float* __restrict__ X, const int* __restrict__ rs,
               const int* __restrict__ cs, bf16* __restrict__ out){
  int node = blockIdx.x, lane = threadIdx.x;
  int s0 = rs[node], s1 = rs[node + 1];
  float ax = 0.f, ay = 0.f;
  int e = s0;
  for (; e + 4 <= s1; e += 4){
    int c0 = cs[e], c1 = cs[e+1], c2 = cs[e+2], c3 = cs[e+3];
    float2 v0 = ((const float2*)(X + (size_t)c0 * 128))[lane];
    float2 v1 = ((const float2*)(X + (size_t)c1 * 128))[lane];
    float2 v2 = ((const float2*)(X + (size_t)c2 * 128))[lane];
    float2 v3 = ((const float2*)(X + (size_t)c3 * 128))[lane];
    ax += (v0.x + v1.x) + (v2.x + v3.x);
    ay += (v0.y + v1.y) + (v2.y + v3.y);
  }
  for (; e < s1; ++e){
    float2 v = ((const float2*)(X + (size_t)cs[e] * 128))[lane];
    ax += v.x; ay += v.y;
  }
  float inv = 1.f / fmaxf((float)(s1 - s0), 1.f);
  ((uint32_t*)(out + (size_t)node * 128))[lane] = pk2(ax * inv, ay * inv);
}

__global__ __launch_bounds__(64)
void k_agg128b(const bf16* __restrict__ X, const int* __restrict__ rs,
               const int* __restrict__ cs, bf16* __restrict__ out){
  int node = blockIdx.x, lane = threadIdx.x;
  int s0 = rs[node], s1 = rs[node + 1];
  float ax = 0.f, ay = 0.f;
  int e = s0;
  for (; e + 4 <= s1; e += 4){
    int c0 = cs[e], c1 = cs[e+1], c2 = cs[e+2], c3 = cs[e+3];
    uint32_t v0 = ((const uint32_t*)(X + (size_t)c0 * 128))[lane];
    uint32_t v1 = ((const uint32_t*)(X + (size_t)c1 * 128))[lane];
    uint32_t v2 = ((const uint32_t*)(X + (size_t)c2 * 128))[lane];
    uint32_t v3 = ((const uint32_t*)(X + (size_t)c3 * 128))[lane];
    ax += bf2f((unsigned short)(v0 & 0xffffu)) + bf2f((unsigned short)(v1 & 0xffffu))
        + bf2f((unsigned short)(v2 & 0xffffu)) + bf2f((unsigned short)(v3 & 0xffffu));
    ay += bf2f((unsigned short)(v0 >> 16)) + bf2f((unsigned short)(v1 >> 16))
        + bf2f((unsigned short)(v2 >> 16)) + bf2f((unsigned short)(v3 >> 16));
  }
  for (; e < s1; ++e){
    uint32_t v = ((const uint32_t*)(X + (size_t)cs[e] * 128))[lane];
    ax += bf2f((unsigned short)(v & 0xffffu));
    ay += bf2f((unsigned short)(v >> 16));
  }
  float inv = 1.f / fmaxf((float)(s1 - s0), 1.f);
  ((uint32_t*)(out + (size_t)node * 128))[lane] = pk2(ax * inv, ay * inv);
}

// ---------------- weight prep: bf16 transposed [N][K] layouts ----------------
// Bt_ha rows n in [0,256), k in [0,384): [Wl1g[1]^T | Wl1g[2]^T | (Wr1g[1]+Wr1g[2])^T]
__global__ void k_wt1a(const float* __restrict__ Wl1g, const float* __restrict__ Wr1g,
                       bf16* __restrict__ dst){
  int n = blockIdx.y, k = blockIdx.x * 128 + threadIdx.x;   // k < 384
  int seg = k >> 7, kk = k & 127;
  float v;
  if (seg == 0)      v = Wl1g[(size_t)(128 + kk) * 256 + n];
  else if (seg == 1) v = Wl1g[(size_t)(256 + kk) * 256 + n];
  else               v = Wr1g[(size_t)(128 + kk) * 256 + n] + Wr1g[(size_t)(256 + kk) * 256 + n];
  dst[(size_t)n * 384 + k] = f2bf(v);
}

// Bt_ht rows n in [0,256), k in [0,256): [Wl1g[0]^T | Wr1g[0]^T]
__global__ void k_wt1t(const float* __restrict__ Wl1g, const float* __restrict__ Wr1g,
                       bf16* __restrict__ dst){
  int n = blockIdx.y, k = blockIdx.x * 128 + threadIdx.x;   // k < 256
  int kk = k & 127;
  float v = (k < 128) ? Wl1g[(size_t)kk * 256 + n] : Wr1g[(size_t)kk * 256 + n];
  dst[(size_t)n * 256 + k] = f2bf(v);
}

// BT2: 5 strips of O rows each, K=256:
// strip0 Wl2g[0]^T, 1 Wl2g[1]^T, 2 Wl2g[2]^T, 3 (Wr2g[1]+Wr2g[2])^T, 4 Wr2g[0]^T
__global__ void k_wt2(const float* __restrict__ Wl2g, const float* __restrict__ Wr2g,
                      int O, bf16* __restrict__ dst){
  int n = blockIdx.y, k = blockIdx.x * 128 + threadIdx.x;   // n < 5*O, k < 256
  int strip = n / O, r = n - strip * O;
  float v;
  if (strip < 3)      v = Wl2g[(size_t)strip * 256 * O + (size_t)k * O + r];
  else if (strip == 3) v = Wr2g[(size_t)256 * O + (size_t)k * O + r]
                         + Wr2g[(size_t)512 * O + (size_t)k * O + r];
  else                v = Wr2g[(size_t)k * O + r];
  dst[(size_t)n * 256 + k] = f2bf(v);
}

__global__ void k_bias(const float* __restrict__ b1g, const float* __restrict__ b2g,
                       int O, float* __restrict__ bc1, float* __restrict__ bc2){
  int t = threadIdx.x;
  bc1[t] = b1g[256 + t] + b1g[512 + t];
  if (t < O) bc2[t] = b2g[O + t] + b2g[2 * O + t];
}

// ---------------- MFMA GEMM: C[M,N] = concat_K(A segs) @ Bt^T (+bias) ----------------
// A segs of K=128 each (bf16 or f32 per af32 bitmask); Bt is [N][Ktot] bf16 row-major.
__device__ __forceinline__ void store1c(float* p, float v){ *p = v; }
__device__ __forceinline__ void store1c(bf16* p, float v){ *p = f2bf(v); }

template<typename TC>
__global__ __launch_bounds__(256)
void k_gemm_mfma(const void* __restrict__ A0v, const void* __restrict__ A1v,
                 const void* __restrict__ A2v, int lda, int af32,
                 const bf16* __restrict__ Bt, int ldb,
                 const float* __restrict__ bias,
                 TC* __restrict__ C, int ldc, int M, int N, int Ktot){
  __shared__ bf16 As[128][40];   // stride 80B: balanced banks for b128 frag reads
  __shared__ bf16 Bs[64][40];
  const int tid = threadIdx.x;
  const int w = tid >> 6, l = tid & 63;
  const int r0 = blockIdx.y * 128, c0 = blockIdx.x * 64;

  f32x4 acc[2][4] = {};

  const int sm = tid >> 1, sk = (tid & 1) * 16;   // A staging: row sm, 16 elems
  const int bn = tid >> 2, bk = (tid & 3) * 8;    // B staging: row bn, 8 elems
  const int arow = r0 + sm, brow = c0 + bn;
  const int lr = l & 15, g8 = (l >> 4) * 8;

  for (int kk = 0; kk < Ktot; kk += 32){
    const int seg = kk >> 7, koff = (kk & 127) + sk;
    const void* Ap = (seg == 0) ? A0v : ((seg == 1) ? A1v : A2v);
    uint4 wa0 = {0,0,0,0}, wa1 = {0,0,0,0};
    if (arow < M){
      if ((af32 >> seg) & 1){
        const float4* p = (const float4*)((const float*)Ap + (size_t)arow * lda + koff);
        float4 f0 = p[0], f1 = p[1], f2 = p[2], f3 = p[3];
        wa0.x = pk2(f0.x, f0.y); wa0.y = pk2(f0.z, f0.w);
        wa0.z = pk2(f1.x, f1.y); wa0.w = pk2(f1.z, f1.w);
        wa1.x = pk2(f2.x, f2.y); wa1.y = pk2(f2.z, f2.w);
        wa1.z = pk2(f3.x, f3.y); wa1.w = pk2(f3.z, f3.w);
      } else {
        const uint4* p = (const uint4*)((const bf16*)Ap + (size_t)arow * lda + koff);
        wa0 = p[0]; wa1 = p[1];
      }
    }
    uint4 wb = {0,0,0,0};
    if (brow < N) wb = *(const uint4*)(Bt + (size_t)brow * ldb + kk + bk);
    __syncthreads();
    *(uint4*)&As[sm][sk]     = wa0;
    *(uint4*)&As[sm][sk + 8] = wa1;
    *(uint4*)&Bs[bn][bk]     = wb;
    __syncthreads();
    short8 a0 = *(const short8*)&As[w * 32      + lr][g8];
    short8 a1 = *(const short8*)&As[w * 32 + 16 + lr][g8];
    short8 b0 = *(const short8*)&Bs[     lr][g8];
    short8 b1 = *(const short8*)&Bs[16 + lr][g8];
    short8 b2 = *(const short8*)&Bs[32 + lr][g8];
    short8 b3 = *(const short8*)&Bs[48 + lr][g8];
    acc[0][0] = __builtin_amdgcn_mfma_f32_16x16x32_bf16(a0, b0, acc[0][0], 0, 0, 0);
    acc[0][1] = __builtin_amdgcn_mfma_f32_16x16x32_bf16(a0, b1, acc[0][1], 0, 0, 0);
    acc[0][2] = __builtin_amdgcn_mfma_f32_16x16x32_bf16(a0, b2, acc[0][2], 0, 0, 0);
    acc[0][3] = __builtin_amdgcn_mfma_f32_16x16x32_bf16(a0, b3, acc[0][3], 0, 0, 0);
    acc[1][0] = __builtin_amdgcn_mfma_f32_16x16x32_bf16(a1, b0, acc[1][0], 0, 0, 0);
    acc[1][1] = __builtin_amdgcn_mfma_f32_16x16x32_bf16(a1, b1, acc[1][1], 0, 0, 0);
    acc[1][2] = __builtin_amdgcn_mfma_f32_16x16x32_bf16(a1, b2, acc[1][2], 0, 0, 0);
    acc[1][3] = __builtin_amdgcn_mfma_f32_16x16x32_bf16(a1, b3, acc[1][3], 0, 0, 0);
  }
  // epilogue: C/D map col=lane&15, row=(lane>>4)*4+reg  [verified m89/m91]
  #pragma unroll
  for (int rt = 0; rt < 2; ++rt){
    #pragma unroll
    for (int ct = 0; ct < 4; ++ct){
      #pragma unroll
      for (int r = 0; r < 4; ++r){
        int row = r0 + w * 32 + rt * 16 + (l >> 4) * 4 + r;
        int col = c0 + ct * 16 + lr;
        if (row < M && col < N){
          float v = acc[rt][ct][r];
          if (bias) v += bias[col];
          store1c(&C[(size_t)row * ldc + col], v);
        }
      }
    }
  }
}

// ---------------- fused relu + jax-exact dropout(0.5), in-place bf16 ----------------
__global__ void k_relu_drop(bf16* __restrict__ h, int n, uint32_t k0, uint32_t k1){
  int i = blockIdx.x * 256 + threadIdx.x;
  if (i >= n) return;
  uint32_t o0, o1;
  tf2x32(k0, k1, 0u, (uint32_t)i, &o0, &o1);
  uint32_t bits = o0 ^ o1;
  float a = fmaxf(bf2f(h[i]), 0.f);
  h[i] = (bits >> 31) ? (bf16)0 : f2bf(a + a);
}

// ---------------- fused assembles: mean-gather (all 3 heads) + residual + log_softmax ----------------
__global__ __launch_bounds__(256)
void k_assemble_t(const bf16* __restrict__ z, const int* __restrict__ rs,
                  const int* __restrict__ cs,
                  float* __restrict__ o0, float* __restrict__ o1, float* __restrict__ o2){
  const int node = blockIdx.x, t = threadIdx.x;
  const bool act = t < 179;
  const int h = (t < 129) ? 0 : ((t < 161) ? 1 : 2);
  const int base = (h == 0) ? 0 : ((h == 1) ? 129 : 161);
  const int Oh = (h == 0) ? 129 : ((h == 1) ? 32 : 18);
  float acc = 0.f;
  const int s0 = rs[node], s1 = rs[node + 1];
  int e = s0;
  for (; e + 4 <= s1; e += 4){
    size_t c0 = (size_t)cs[e] * 179, c1 = (size_t)cs[e+1] * 179;
    size_t c2 = (size_t)cs[e+2] * 179, c3 = (size_t)cs[e+3] * 179;
    if (act){
      float v0 = bf2f(z[c0 + t]), v1 = bf2f(z[c1 + t]);
      float v2 = bf2f(z[c2 + t]), v3 = bf2f(z[c3 + t]);
      acc += (v0 + v1) + (v2 + v3);
    }
  }
  for (; e < s1; ++e)
    if (act) acc += bf2f(z[(size_t)cs[e] * 179 + t]);
  const float inv = 1.f / fmaxf((float)(s1 - s0), 1.f);
  float* orow = ((h == 0) ? o0 : ((h == 1) ? o1 : o2)) + (size_t)node * Oh + (t - base);
  float v = 0.f;
  if (act) v = *orow + acc * inv;
  __shared__ float sb[179];
  __shared__ float lse[3];
  if (act) sb[t] = v;
  __syncthreads();
  const int wv = t >> 6, ln = t & 63;
  if (wv < 3){
    const int b = (wv == 0) ? 0 : ((wv == 1) ? 129 : 161);
    const int W = (wv == 0) ? 129 : ((wv == 1) ? 32 : 18);
    float m = -3.4e38f;
    for (int i = ln; i < W; i += 64) m = fmaxf(m, sb[b + i]);
    #pragma unroll
    for (int o = 32; o; o >>= 1) m = fmaxf(m, __shfl_xor(m, o));
    float s = 0.f;
    for (int i = ln; i < W; i += 64) s += expf(sb[b + i] - m);
    #pragma unroll
    for (int o = 32; o; o >>= 1) s += __shfl_xor(s, o);
    if (ln == 0) lse[wv] = m + logf(s);
  }
  __syncthreads();
  if (act) *orow = v - lse[h];
}

__global__ __launch_bounds__(256)
void k_assemble_a(const bf16* __restrict__ zT, const bf16* __restrict__ zA,
                  const int* __restrict__ rs_ta, const int* __restrict__ cs_ta,
                  const int* __restrict__ rs_aa, const int* __restrict__ cs_aa,
                  float* __restrict__ o0, float* __restrict__ o1, float* __restrict__ o2){
  const int node = blockIdx.x, t = threadIdx.x;
  const bool act = t < 179;
  const int h = (t < 129) ? 0 : ((t < 161) ? 1 : 2);
  const int base = (h == 0) ? 0 : ((h == 1) ? 129 : 161);
  const int Oh = (h == 0) ? 129 : ((h == 1) ? 32 : 18);
  float accT = 0.f, accA = 0.f;
  int s0 = rs_ta[node], s1 = rs_ta[node + 1];
  int e = s0;
  for (; e + 4 <= s1; e += 4){
    size_t c0 = (size_t)cs_ta[e] * 179, c1 = (size_t)cs_ta[e+1] * 179;
    size_t c2 = (size_t)cs_ta[e+2] * 179, c3 = (size_t)cs_ta[e+3] * 179;
    if (act){
      float v0 = bf2f(zT[c0 + t]), v1 = bf2f(zT[c1 + t]);
      float v2 = bf2f(zT[c2 + t]), v3 = bf2f(zT[c3 + t]);
      accT += (v0 + v1) + (v2 + v3);
    }
  }
  for (; e < s1; ++e)
    if (act) accT += bf2f(zT[(size_t)cs_ta[e] * 179 + t]);
  const float invT = 1.f / fmaxf((float)(s1 - s0), 1.f);
  s0 = rs_aa[node]; s1 = rs_aa[node + 1];
  e = s0;
  for (; e + 4 <= s1; e += 4){
    size_t c0 = (size_t)cs_aa[e] * 179, c1 = (size_t)cs_aa[e+1] * 179;
    size_t c2 = (size_t)cs_aa[e+2] * 179, c3 = (size_t)cs_aa[e+3] * 179;
    if (act){
      float v0 = bf2f(zA[c0 + t]), v1 = bf2f(zA[c1 + t]);
      float v2 = bf2f(zA[c2 + t]), v3 = bf2f(zA[c3 + t]);
      accA += (v0 + v1) + (v2 + v3);
    }
  }
  for (; e < s1; ++e)
    if (act) accA += bf2f(zA[(size_t)cs_aa[e] * 179 + t]);
  const float invA = 1.f / fmaxf((float)(s1 - s0), 1.f);
  float* orow = ((h == 0) ? o0 : ((h == 1) ? o1 : o2)) + (size_t)node * Oh + (t - base);
  float v = 0.f;
  if (act) v = *orow + accT * invT + accA * invA;
  __shared__ float sb[179];
  __shared__ float lse[3];
  if (act) sb[t] = v;
  __syncthreads();
  const int wv = t >> 6, ln = t & 63;
  if (wv < 3){
    const int b = (wv == 0) ? 0 : ((wv == 1) ? 129 : 161);
    const int W = (wv == 0) ? 129 : ((wv == 1) ? 32 : 18);
    float m = -3.4e38f;
    for (int i = ln; i < W; i += 64) m = fmaxf(m, sb[b + i]);
    #pragma unroll
    for (int o = 32; o; o >>= 1) m = fmaxf(m, __shfl_xor(m, o));
    float s = 0.f;
    for (int i = ln; i < W; i += 64) s += expf(sb[b + i] - m);
    #pragma unroll
    for (int o = 32; o; o >>= 1) s += __shfl_xor(s, o);
    if (ln == 0) lse[wv] = m + logf(s);
  }
  __syncthreads();
  if (act) *orow = v - lse[h];
}

// ---------------- host ----------------
template<typename TC>
static void launch_mm(const void* A0, const void* A1, const void* A2, int lda, int af32,
                      const bf16* Bt, int ldb, const float* bias,
                      TC* C, int ldc, int M, int N, int Kt, hipStream_t s){
  dim3 grid((N + 63) / 64, (M + 127) / 128);
  k_gemm_mfma<TC><<<grid, 256, 0, s>>>(A0, A1, A2, lda, af32, Bt, ldb, bias, C, ldc, M, N, Kt);
}

extern "C" void kernel_launch(void* const* d_in, const int* in_sizes, int n_in,
                              void* d_out, int out_size, void* d_ws, size_t ws_size,
                              hipStream_t stream){
  (void)n_in; (void)out_size; (void)ws_size;
  const float* xa  = (const float*)d_in[0];
  const float* xt  = (const float*)d_in[1];
  const int*   e_at = (const int*)d_in[2];
  const int*   e_ta = (const int*)d_in[3];
  const int*   e_aa = (const int*)d_in[4];
  const float* Wl1 = (const float*)d_in[5];
  const float* Wr1 = (const float*)d_in[6];
  const float* b1  = (const float*)d_in[7];
  const float* Wl2_[3] = {(const float*)d_in[8],  (const float*)d_in[11], (const float*)d_in[14]};
  const float* Wr2_[3] = {(const float*)d_in[9],  (const float*)d_in[12], (const float*)d_in[15]};
  const float* b2_[3]  = {(const float*)d_in[10], (const float*)d_in[13], (const float*)d_in[16]};

  const int NA = in_sizes[0] / 128;
  const int NT = in_sizes[1] / 128;
  const int EAT = in_sizes[2] / 2, ETA = in_sizes[3] / 2, EAA = in_sizes[4] / 2;
  const int Ov[3] = {129, 32, 18};
  const int ZW = 179;             // fused z width (129+32+18)
  const int og[3] = {0, 129, 161};

  // -------- workspace layout (~281 MB) --------
  char* Wp = (char*)d_ws;
  size_t off = 0;
  auto alloc = [&](size_t bytes)->char*{
    char* p = Wp + off; off = (off + bytes + 255) & ~(size_t)255; return p;
  };
  bf16* m_at = (bf16*)alloc((size_t)NT * 128 * 2);
  bf16* m_ta = (bf16*)alloc((size_t)NA * 128 * 2);
  bf16* m_aa = (bf16*)alloc((size_t)NA * 128 * 2);
  bf16* xt_b = (bf16*)alloc((size_t)NT * 128 * 2);
  bf16* h_a  = (bf16*)alloc((size_t)NA * 256 * 2);
  bf16* h_t  = (bf16*)alloc((size_t)NT * 256 * 2);
  bf16* zA_at = (bf16*)alloc((size_t)NA * ZW * 2);
  bf16* zT_ta = (bf16*)alloc((size_t)NT * ZW * 2);
  bf16* zA_aa = (bf16*)alloc((size_t)NA * ZW * 2);
  bf16* Bt_ha = (bf16*)alloc((size_t)256 * 384 * 2);
  bf16* Bt_ht = (bf16*)alloc((size_t)256 * 256 * 2);
  bf16* BT2   = (bf16*)alloc((size_t)5 * 129 * 256 * 2);
  float* bc1  = (float*)alloc(256 * 4);
  float* bc2  = (float*)alloc(129 * 4);
  int* rs_at  = (int*)alloc((size_t)(NT + 1) * 4);
  int* rs_ta  = (int*)alloc((size_t)(NA + 1) * 4);
  int* rs_aa  = (int*)alloc((size_t)(NA + 1) * 4);
  int* cur_at = (int*)alloc((size_t)NT * 4);
  int* cur_ta = (int*)alloc((size_t)NA * 4);
  int* cur_aa = (int*)alloc((size_t)NA * 4);
  int* bsum   = (int*)alloc(2048 * 4);
  int* cs_at  = (int*)alloc((size_t)EAT * 4);
  int* cs_ta  = (int*)alloc((size_t)ETA * 4);
  int* cs_aa  = (int*)alloc((size_t)EAA * 4);

  // bf16 copy of xt (for m_ta gather); xa stays f32 (GEMM converts in staging)
  k_f2bf<<<(NT * 128 / 4 + 255) / 256, 256, 0, stream>>>(xt, xt_b, NT * 128 / 4);

  // -------- CSR build (shared by all 3 GNNs) --------
  auto build_csr = [&](const int* edges, int E, int n, int* rs, int* cur, int* cs){
    int ebl = (E + 255) / 256, nbl = (n + 255) / 256;
    k_zeroi<<<nbl, 256, 0, stream>>>(cur, n);
    k_deg<<<ebl, 256, 0, stream>>>(edges + E, cur, E);
    k_scan_partial<<<nbl, 256, 0, stream>>>(cur, rs, bsum, n);
    k_scan_bsum<<<1, 1024, 0, stream>>>(bsum, nbl, rs + n);
    k_scan_add<<<nbl, 256, 0, stream>>>(rs, bsum, n);
    k_zeroi<<<nbl, 256, 0, stream>>>(cur, n);
    k_fill<<<ebl, 256, 0, stream>>>(edges, edges + E, rs, cur, cs, E);
  };
  build_csr(e_at, EAT, NT, rs_at, cur_at, cs_at);
  build_csr(e_ta, ETA, NA, rs_ta, cur_ta, cs_ta);
  build_csr(e_aa, EAA, NA, rs_aa, cur_aa, cs_aa);

  // -------- layer-1 mean aggregations (g-invariant) --------
  k_agg128f<<<NT, 64, 0, stream>>>(xa,   rs_at, cs_at, m_at);
  k_agg128b<<<NA, 64, 0, stream>>>(xt_b, rs_ta, cs_ta, m_ta);
  k_agg128f<<<NA, 64, 0, stream>>>(xa,   rs_aa, cs_aa, m_aa);

  // d_out head base offsets
  size_t offA[3], offT[3], cum = 0;
  for (int g = 0; g < 3; ++g){
    offA[g] = cum; offT[g] = cum + (size_t)NA * Ov[g];
    cum += (size_t)(NA + NT) * Ov[g];
  }

  for (int g = 0; g < 3; ++g){
    const int O = Ov[g];
    float* outA = (float*)d_out + offA[g];
    float* outT = (float*)d_out + offT[g];
    const float* Wl1g = Wl1 + (size_t)(3 * g) * 128 * 256;
    const float* Wr1g = Wr1 + (size_t)(3 * g) * 128 * 256;
    const float* b1g  = b1  + (size_t)(3 * g) * 256;

    // weight prep (bf16, transposed, combined)
    k_wt1a<<<dim3(3, 256), 128, 0, stream>>>(Wl1g, Wr1g, Bt_ha);
    k_wt1t<<<dim3(2, 256), 128, 0, stream>>>(Wl1g, Wr1g, Bt_ht);
    k_wt2 <<<dim3(2, 5 * O), 128, 0, stream>>>(Wl2_[g], Wr2_[g], O, BT2);
    k_bias<<<1, 256, 0, stream>>>(b1g, b2_[g], O, bc1, bc2);

    // layer 1 (MFMA): h_a = [m_ta|m_aa|xa] @ Bt_ha^T + bc1 ; h_t = [m_at|xt] @ Bt_ht^T + b1g[0]
    launch_mm<bf16>(m_ta, m_aa, xa, 128, 0b100, Bt_ha, 384, bc1, h_a, 256, NA, 256, 384, stream);
    launch_mm<bf16>(m_at, xt_b, xt_b, 128, 0b000, Bt_ht, 256, b1g, h_t, 256, NT, 256, 256, stream);

    // relu + dropout (jax threefry, verified R2)
    uint32_t kg0, kg1, ka0, ka1, kt0, kt1;
    tf2x32(0u, 42u, 0u, (uint32_t)g, &kg0, &kg1);
    tf2x32(kg0, kg1, 0u, 0u, &ka0, &ka1);
    tf2x32(kg0, kg1, 0u, 1u, &kt0, &kt1);
    k_relu_drop<<<(NA * 256 + 255) / 256, 256, 0, stream>>>(h_a, NA * 256, ka0, ka1);
    k_relu_drop<<<(NT * 256 + 255) / 256, 256, 0, stream>>>(h_t, NT * 256, kt0, kt1);

    // layer 2 transforms (transform-then-aggregate); z into fused [node][179] buffers
    launch_mm<bf16>(h_a, h_a + 128, h_a, 256, 0, BT2 + (size_t)0 * O * 256, 256, nullptr,
                    zA_at + og[g], ZW, NA, O, 256, stream);
    launch_mm<bf16>(h_t, h_t + 128, h_t, 256, 0, BT2 + (size_t)1 * O * 256, 256, nullptr,
                    zT_ta + og[g], ZW, NT, O, 256, stream);
    launch_mm<bf16>(h_a, h_a + 128, h_a, 256, 0, BT2 + (size_t)2 * O * 256, 256, nullptr,
                    zA_aa + og[g], ZW, NA, O, 256, stream);
    // self/residual terms straight into d_out (f32)
    launch_mm<float>(h_a, h_a + 128, h_a, 256, 0, BT2 + (size_t)3 * O * 256, 256, bc2,
                     outA, O, NA, O, 256, stream);
    launch_mm<float>(h_t, h_t + 128, h_t, 256, 0, BT2 + (size_t)4 * O * 256, 256, b2_[g],
                     outT, O, NT, O, 256, stream);
  }

  // -------- fused gather-mean + log_softmax over all 3 heads --------
  k_assemble_t<<<NT, 256, 0, stream>>>(zA_at, rs_at, cs_at,
                                       (float*)d_out + offT[0], (float*)d_out + offT[1],
                                       (float*)d_out + offT[2]);
  k_assemble_a<<<NA, 256, 0, stream>>>(zT_ta, zA_aa, rs_ta, cs_ta, rs_aa, cs_aa,
                                       (float*)d_out + offA[0], (float*)d_out + offA[1],
                                       (float*)d_out + offA[2]);
}

// Round 4
// 2167.874 us; speedup vs baseline: 2.7667x; 1.2499x over previous
//
#include <hip/hip_runtime.h>
#include <stdint.h>
#include <stddef.h>

typedef unsigned short bf16;
typedef __attribute__((ext_vector_type(8))) short short8;   // 8 bf16 (MFMA A/B frag)
typedef __attribute__((ext_vector_type(4))) float f32x4;    // MFMA C/D frag

__device__ __forceinline__ float bf2f(unsigned short u){
  union { uint32_t i; float f; } x; x.i = ((uint32_t)u) << 16; return x.f;
}
__device__ __forceinline__ unsigned short f2bf(float f){
  union { float f; uint32_t i; } x; x.f = f;
  uint32_t r = x.i + 0x7FFFu + ((x.i >> 16) & 1u);  // RNE
  return (unsigned short)(r >> 16);
}
__device__ __forceinline__ uint32_t pk2(float a, float b){
  return (uint32_t)f2bf(a) | ((uint32_t)f2bf(b) << 16);
}

// ---- fp8 e4m3fn encode (RNE) / decode -- internal compression only ----
__device__ __forceinline__ uint8_t f2fp8(float f){
  uint32_t b = __float_as_uint(f);
  uint32_t s = (b >> 24) & 0x80u;
  uint32_t x = b & 0x7fffffffu;
  if (x >= 0x43e00000u) return (uint8_t)(s | 0x7eu);        // |v|>=448 (or NaN) -> ±448
  if (x < 0x3c800000u){                                     // |v| < 2^-6 -> subnormal
    uint32_t q = (uint32_t)rintf(__uint_as_float(x) * 512.f);
    return (uint8_t)(s | q);
  }
  uint32_t lsb = (x >> 20) & 1u;
  x += 0x7ffffu + lsb;                                      // RNE at bit 20
  uint32_t u = (((x >> 23) - 120u) << 3) | ((x >> 20) & 7u);
  if (u > 0x7eu) u = 0x7eu;
  return (uint8_t)(s | u);
}
__device__ __forceinline__ float fp8d(uint8_t u){
  uint32_t e = (u >> 3) & 15u, m = u & 7u;
  float v = (e == 0) ? (float)m * 0.001953125f              // m * 2^-9
                     : ldexpf((float)(8u + m), (int)e - 10);
  return (u & 0x80u) ? -v : v;
}

// ---------------- threefry2x32 (matches harness jax reference; verified R2/R3) ----------------
__host__ __device__ __forceinline__ uint32_t rotl32_(uint32_t x, int d){
  return (x << d) | (x >> (32 - d));
}
__host__ __device__ inline void tf2x32(uint32_t k0, uint32_t k1, uint32_t x0, uint32_t x1,
                                       uint32_t* o0, uint32_t* o1){
  uint32_t k2 = k0 ^ k1 ^ 0x1BD11BDAu;
#define TF_R4(ra,rb,rc,rd) \
  x0 += x1; x1 = rotl32_(x1,ra); x1 ^= x0; \
  x0 += x1; x1 = rotl32_(x1,rb); x1 ^= x0; \
  x0 += x1; x1 = rotl32_(x1,rc); x1 ^= x0; \
  x0 += x1; x1 = rotl32_(x1,rd); x1 ^= x0;
  x0 += k0; x1 += k1;
  TF_R4(13,15,26,6)  x0 += k1; x1 += k2 + 1u;
  TF_R4(17,29,16,24) x0 += k2; x1 += k0 + 2u;
  TF_R4(13,15,26,6)  x0 += k0; x1 += k1 + 3u;
  TF_R4(17,29,16,24) x0 += k1; x1 += k2 + 4u;
  TF_R4(13,15,26,6)  x0 += k2; x1 += k0 + 5u;
  *o0 = x0; *o1 = x1;
#undef TF_R4
}

// ---------------- small utils ----------------
__global__ void k_zeroi(int* __restrict__ p, int n){
  int i = blockIdx.x * 256 + threadIdx.x;
  if (i < n) p[i] = 0;
}
__global__ void k_f2bf(const float* __restrict__ in, bf16* __restrict__ out, int n4){
  int i = blockIdx.x * 256 + threadIdx.x;
  if (i < n4){
    float4 v = ((const float4*)in)[i];
    ushort4 u; u.x = f2bf(v.x); u.y = f2bf(v.y); u.z = f2bf(v.z); u.w = f2bf(v.w);
    ((ushort4*)out)[i] = u;
  }
}

// ---------------- CSR build ----------------
__global__ void k_deg(const int* __restrict__ dst, int* __restrict__ deg, int E){
  int i = blockIdx.x * 256 + threadIdx.x;
  if (i < E) atomicAdd(&deg[dst[i]], 1);
}
__global__ __launch_bounds__(256)
void k_scan_partial(const int* __restrict__ in, int* __restrict__ exc,
                    int* __restrict__ bsum, int n){
  __shared__ int tmp[256];
  int t = threadIdx.x, i = blockIdx.x * 256 + t;
  int v = (i < n) ? in[i] : 0;
  tmp[t] = v; __syncthreads();
  #pragma unroll
  for (int off = 1; off < 256; off <<= 1){
    int u = (t >= off) ? tmp[t - off] : 0; __syncthreads();
    tmp[t] += u; __syncthreads();
  }
  if (i < n) exc[i] = tmp[t] - v;
  if (t == 255) bsum[blockIdx.x] = tmp[255];
}
__global__ __launch_bounds__(1024)
void k_scan_bsum(int* __restrict__ bsum, int nb, int* __restrict__ total_out){
  __shared__ int tmp[1024];
  int t = threadIdx.x;
  int v = (t < nb) ? bsum[t] : 0;
  tmp[t] = v; __syncthreads();
  #pragma unroll
  for (int off = 1; off < 1024; off <<= 1){
    int u = (t >= off) ? tmp[t - off] : 0; __syncthreads();
    tmp[t] += u; __syncthreads();
  }
  if (t < nb) bsum[t] = tmp[t] - v;
  if (t == 1023) *total_out = tmp[1023];
}
__global__ void k_scan_add(int* __restrict__ exc, const int* __restrict__ bsum, int n){
  int i = blockIdx.x * 256 + threadIdx.x;
  if (i < n) exc[i] += bsum[blockIdx.x];
}
__global__ void k_fill(const int* __restrict__ src, const int* __restrict__ dst,
                       const int* __restrict__ rs, int* __restrict__ cur,
                       int* __restrict__ cs, int E){
  int i = blockIdx.x * 256 + threadIdx.x;
  if (i < E){
    int d = dst[i];
    int p = atomicAdd(&cur[d], 1);
    cs[rs[d] + p] = src[i];
  }
}

// ---------------- layer-1 mean aggregation (D=128 bf16), 1 wave/node, unroll-4 ----------------
__global__ __launch_bounds__(64)
void k_agg128b(const bf16* __restrict__ X, const int* __restrict__ rs,
               const int* __restrict__ cs, bf16* __restrict__ out){
  int node = blockIdx.x, lane = threadIdx.x;
  int s0 = rs[node], s1 = rs[node + 1];
  float ax = 0.f, ay = 0.f;
  int e = s0;
  for (; e + 4 <= s1; e += 4){
    int c0 = cs[e], c1 = cs[e+1], c2 = cs[e+2], c3 = cs[e+3];
    uint32_t v0 = ((const uint32_t*)(X + (size_t)c0 * 128))[lane];
    uint32_t v1 = ((const uint32_t*)(X + (size_t)c1 * 128))[lane];
    uint32_t v2 = ((const uint32_t*)(X + (size_t)c2 * 128))[lane];
    uint32_t v3 = ((const uint32_t*)(X + (size_t)c3 * 128))[lane];
    ax += bf2f((unsigned short)(v0 & 0xffffu)) + bf2f((unsigned short)(v1 & 0xffffu))
        + bf2f((unsigned short)(v2 & 0xffffu)) + bf2f((unsigned short)(v3 & 0xffffu));
    ay += bf2f((unsigned short)(v0 >> 16)) + bf2f((unsigned short)(v1 >> 16))
        + bf2f((unsigned short)(v2 >> 16)) + bf2f((unsigned short)(v3 >> 16));
  }
  for (; e < s1; ++e){
    uint32_t v = ((const uint32_t*)(X + (size_t)cs[e] * 128))[lane];
    ax += bf2f((unsigned short)(v & 0xffffu));
    ay += bf2f((unsigned short)(v >> 16));
  }
  float inv = 1.f / fmaxf((float)(s1 - s0), 1.f);
  ((uint32_t*)(out + (size_t)node * 128))[lane] = pk2(ax * inv, ay * inv);
}

// ---------------- weight prep: bf16 transposed [N][K] ----------------
__global__ void k_wt1a(const float* __restrict__ Wl1g, const float* __restrict__ Wr1g,
                       bf16* __restrict__ dst){
  int n = blockIdx.y, k = blockIdx.x * 128 + threadIdx.x;   // k < 384
  int seg = k >> 7, kk = k & 127;
  float v;
  if (seg == 0)      v = Wl1g[(size_t)(128 + kk) * 256 + n];
  else if (seg == 1) v = Wl1g[(size_t)(256 + kk) * 256 + n];
  else               v = Wr1g[(size_t)(128 + kk) * 256 + n] + Wr1g[(size_t)(256 + kk) * 256 + n];
  dst[(size_t)n * 384 + k] = f2bf(v);
}
__global__ void k_wt1t(const float* __restrict__ Wl1g, const float* __restrict__ Wr1g,
                       bf16* __restrict__ dst){
  int n = blockIdx.y, k = blockIdx.x * 128 + threadIdx.x;   // k < 256
  int kk = k & 127;
  float v = (k < 128) ? Wl1g[(size_t)kk * 256 + n] : Wr1g[(size_t)kk * 256 + n];
  dst[(size_t)n * 256 + k] = f2bf(v);
}
// BT2a rows [0,3O): strip0 Wl2[0] (->z_at), strip1 Wl2[2] (->z_aa), strip2 Wr2[1]+Wr2[2] (self_a)
__global__ void k_wt2a(const float* __restrict__ Wl2g, const float* __restrict__ Wr2g,
                       int O, bf16* __restrict__ dst){
  int n = blockIdx.y, k = blockIdx.x * 128 + threadIdx.x;
  int strip = n / O, r = n - strip * O;
  float v;
  if (strip == 0)      v = Wl2g[(size_t)k * O + r];
  else if (strip == 1) v = Wl2g[(size_t)512 * O + (size_t)k * O + r];
  else                 v = Wr2g[(size_t)256 * O + (size_t)k * O + r]
                         + Wr2g[(size_t)512 * O + (size_t)k * O + r];
  dst[(size_t)n * 256 + k] = f2bf(v);
}
// BT2t rows [0,2O): strip0 Wl2[1] (->z_ta), strip1 Wr2[0] (self_t)
__global__ void k_wt2t(const float* __restrict__ Wl2g, const float* __restrict__ Wr2g,
                       int O, bf16* __restrict__ dst){
  int n = blockIdx.y, k = blockIdx.x * 128 + threadIdx.x;
  int strip = n / O, r = n - strip * O;
  float v = (strip == 0) ? Wl2g[(size_t)256 * O + (size_t)k * O + r]
                         : Wr2g[(size_t)k * O + r];
  dst[(size_t)n * 256 + k] = f2bf(v);
}
__global__ void k_bias(const float* __restrict__ b1g, const float* __restrict__ b2g,
                       int O, float* __restrict__ bc1, float* __restrict__ bc2){
  int t = threadIdx.x;
  bc1[t] = b1g[256 + t] + b1g[512 + t];
  if (t < O) bc2[t] = b2g[O + t] + b2g[2 * O + t];
}

// ---------------- MFMA GEMM with fused epilogues ----------------
// EPI 0: h = relu+dropout(acc + bias) -> bf16 hC (ldc=256), threefry keys k0,k1
// EPI 1: 3 strips of O cols: [0,O)->z0 fp8; [O,2O)->z1 fp8; [2O,3O)->outF f32 + bias
// EPI 2: 2 strips of O cols: [0,O)->z0 fp8; [O,2O)->outF f32 + bias
template<int EPI>
__global__ __launch_bounds__(256)
void k_gemm_mfma(const bf16* __restrict__ A0, const bf16* __restrict__ A1,
                 const bf16* __restrict__ A2, int lda,
                 const bf16* __restrict__ Bt, int ldb,
                 int M, int N, int Ktot,
                 bf16* __restrict__ hC,
                 uint8_t* __restrict__ z0, uint8_t* __restrict__ z1,
                 float* __restrict__ outF, const float* __restrict__ bias,
                 int O, int zoff, uint32_t dk0, uint32_t dk1){
  __shared__ bf16 As[128][40];
  __shared__ bf16 Bs[64][40];
  const int tid = threadIdx.x;
  const int w = tid >> 6, l = tid & 63;
  const int r0 = blockIdx.y * 128, c0 = blockIdx.x * 64;

  f32x4 acc[2][4] = {};

  const int sm = tid >> 1, sk = (tid & 1) * 16;
  const int bn = tid >> 2, bk = (tid & 3) * 8;
  const int arow = r0 + sm, brow = c0 + bn;
  const int lr = l & 15, g8 = (l >> 4) * 8;

  for (int kk = 0; kk < Ktot; kk += 32){
    const int seg = kk >> 7, koff = (kk & 127) + sk;
    const bf16* Ap = (seg == 0) ? A0 : ((seg == 1) ? A1 : A2);
    uint4 wa0 = {0,0,0,0}, wa1 = {0,0,0,0};
    if (arow < M){
      const uint4* p = (const uint4*)(Ap + (size_t)arow * lda + koff);
      wa0 = p[0]; wa1 = p[1];
    }
    uint4 wb = {0,0,0,0};
    if (brow < N) wb = *(const uint4*)(Bt + (size_t)brow * ldb + kk + bk);
    __syncthreads();
    *(uint4*)&As[sm][sk]     = wa0;
    *(uint4*)&As[sm][sk + 8] = wa1;
    *(uint4*)&Bs[bn][bk]     = wb;
    __syncthreads();
    short8 a0 = *(const short8*)&As[w * 32      + lr][g8];
    short8 a1 = *(const short8*)&As[w * 32 + 16 + lr][g8];
    short8 b0 = *(const short8*)&Bs[     lr][g8];
    short8 b1 = *(const short8*)&Bs[16 + lr][g8];
    short8 b2 = *(const short8*)&Bs[32 + lr][g8];
    short8 b3 = *(const short8*)&Bs[48 + lr][g8];
    acc[0][0] = __builtin_amdgcn_mfma_f32_16x16x32_bf16(a0, b0, acc[0][0], 0, 0, 0);
    acc[0][1] = __builtin_amdgcn_mfma_f32_16x16x32_bf16(a0, b1, acc[0][1], 0, 0, 0);
    acc[0][2] = __builtin_amdgcn_mfma_f32_16x16x32_bf16(a0, b2, acc[0][2], 0, 0, 0);
    acc[0][3] = __builtin_amdgcn_mfma_f32_16x16x32_bf16(a0, b3, acc[0][3], 0, 0, 0);
    acc[1][0] = __builtin_amdgcn_mfma_f32_16x16x32_bf16(a1, b0, acc[1][0], 0, 0, 0);
    acc[1][1] = __builtin_amdgcn_mfma_f32_16x16x32_bf16(a1, b1, acc[1][1], 0, 0, 0);
    acc[1][2] = __builtin_amdgcn_mfma_f32_16x16x32_bf16(a1, b2, acc[1][2], 0, 0, 0);
    acc[1][3] = __builtin_amdgcn_mfma_f32_16x16x32_bf16(a1, b3, acc[1][3], 0, 0, 0);
  }
  // C/D map: col=lane&15, row=(lane>>4)*4+reg  [verified]
  #pragma unroll
  for (int rt = 0; rt < 2; ++rt){
    #pragma unroll
    for (int ct = 0; ct < 4; ++ct){
      #pragma unroll
      for (int r = 0; r < 4; ++r){
        int row = r0 + w * 32 + rt * 16 + (l >> 4) * 4 + r;
        int col = c0 + ct * 16 + lr;
        if (row < M && col < N){
          float v = acc[rt][ct][r];
          if (EPI == 0){
            v += bias[col];
            uint32_t o0, o1;
            tf2x32(dk0, dk1, 0u, (uint32_t)(row * 256 + col), &o0, &o1);
            float a = fmaxf(v, 0.f) * 2.f;
            hC[(size_t)row * 256 + col] = ((o0 ^ o1) >> 31) ? (bf16)0 : f2bf(a);
          } else {
            int s = (col >= O) + (EPI == 1 ? (col >= 2 * O) : 0);
            int lc = col - s * O;
            const int fs = (EPI == 1) ? 2 : 1;
            if (s == fs){
              outF[(size_t)row * O + lc] = v + bias[lc];
            } else {
              uint8_t* d = (s == 0) ? z0 : z1;
              d[(size_t)row * 192 + zoff + lc] = f2fp8(v);
            }
          }
        }
      }
    }
  }
}

// ---------------- fused assembles: fp8 mean-gather (3 heads) + residual + log_softmax ----------------
__global__ __launch_bounds__(192)
void k_assemble_t(const uint8_t* __restrict__ z, const int* __restrict__ rs,
                  const int* __restrict__ cs,
                  float* __restrict__ o0, float* __restrict__ o1, float* __restrict__ o2){
  __shared__ float lut[256];
  __shared__ float sb[179];
  __shared__ float lse[3];
  const int node = blockIdx.x, t = threadIdx.x;
  lut[t] = fp8d((uint8_t)t);
  if (t < 64) lut[t + 192] = fp8d((uint8_t)(t + 192));
  const bool act = t < 179;
  const int h = (t < 129) ? 0 : ((t < 161) ? 1 : 2);
  const int base = (h == 0) ? 0 : ((h == 1) ? 129 : 161);
  const int Oh = (h == 0) ? 129 : ((h == 1) ? 32 : 18);
  const int s0 = rs[node], s1 = rs[node + 1];
  __syncthreads();
  float acc = 0.f;
  int e = s0;
  for (; e + 4 <= s1; e += 4){
    size_t c0 = (size_t)cs[e] * 192, c1 = (size_t)cs[e+1] * 192;
    size_t c2 = (size_t)cs[e+2] * 192, c3 = (size_t)cs[e+3] * 192;
    if (act){
      float v0 = lut[z[c0 + t]], v1 = lut[z[c1 + t]];
      float v2 = lut[z[c2 + t]], v3 = lut[z[c3 + t]];
      acc += (v0 + v1) + (v2 + v3);
    }
  }
  for (; e < s1; ++e)
    if (act) acc += lut[z[(size_t)cs[e] * 192 + t]];
  const float inv = 1.f / fmaxf((float)(s1 - s0), 1.f);
  float* orow = ((h == 0) ? o0 : ((h == 1) ? o1 : o2)) + (size_t)node * Oh + (t - base);
  float v = 0.f;
  if (act) v = *orow + acc * inv;
  if (act) sb[t] = v;
  __syncthreads();
  const int wv = t >> 6, ln = t & 63;
  {
    const int b = (wv == 0) ? 0 : ((wv == 1) ? 129 : 161);
    const int W = (wv == 0) ? 129 : ((wv == 1) ? 32 : 18);
    float m = -3.4e38f;
    for (int i = ln; i < W; i += 64) m = fmaxf(m, sb[b + i]);
    #pragma unroll
    for (int o = 32; o; o >>= 1) m = fmaxf(m, __shfl_xor(m, o));
    float s = 0.f;
    for (int i = ln; i < W; i += 64) s += expf(sb[b + i] - m);
    #pragma unroll
    for (int o = 32; o; o >>= 1) s += __shfl_xor(s, o);
    if (ln == 0) lse[wv] = m + logf(s);
  }
  __syncthreads();
  if (act) *orow = v - lse[h];
}

__global__ __launch_bounds__(192)
void k_assemble_a(const uint8_t* __restrict__ zT, const uint8_t* __restrict__ zA,
                  const int* __restrict__ rs_ta, const int* __restrict__ cs_ta,
                  const int* __restrict__ rs_aa, const int* __restrict__ cs_aa,
                  float* __restrict__ o0, float* __restrict__ o1, float* __restrict__ o2){
  __shared__ float lut[256];
  __shared__ float sb[179];
  __shared__ float lse[3];
  const int node = blockIdx.x, t = threadIdx.x;
  lut[t] = fp8d((uint8_t)t);
  if (t < 64) lut[t + 192] = fp8d((uint8_t)(t + 192));
  const bool act = t < 179;
  const int h = (t < 129) ? 0 : ((t < 161) ? 1 : 2);
  const int base = (h == 0) ? 0 : ((h == 1) ? 129 : 161);
  const int Oh = (h == 0) ? 129 : ((h == 1) ? 32 : 18);
  __syncthreads();
  float accT = 0.f, accA = 0.f;
  int s0 = rs_ta[node], s1 = rs_ta[node + 1];
  int e = s0;
  for (; e + 4 <= s1; e += 4){
    size_t c0 = (size_t)cs_ta[e] * 192, c1 = (size_t)cs_ta[e+1] * 192;
    size_t c2 = (size_t)cs_ta[e+2] * 192, c3 = (size_t)cs_ta[e+3] * 192;
    if (act){
      float v0 = lut[zT[c0 + t]], v1 = lut[zT[c1 + t]];
      float v2 = lut[zT[c2 + t]], v3 = lut[zT[c3 + t]];
      accT += (v0 + v1) + (v2 + v3);
    }
  }
  for (; e < s1; ++e)
    if (act) accT += lut[zT[(size_t)cs_ta[e] * 192 + t]];
  const float invT = 1.f / fmaxf((float)(s1 - s0), 1.f);
  s0 = rs_aa[node]; s1 = rs_aa[node + 1];
  e = s0;
  for (; e + 4 <= s1; e += 4){
    size_t c0 = (size_t)cs_aa[e] * 192, c1 = (size_t)cs_aa[e+1] * 192;
    size_t c2 = (size_t)cs_aa[e+2] * 192, c3 = (size_t)cs_aa[e+3] * 192;
    if (act){
      float v0 = lut[zA[c0 + t]], v1 = lut[zA[c1 + t]];
      float v2 = lut[zA[c2 + t]], v3 = lut[zA[c3 + t]];
      accA += (v0 + v1) + (v2 + v3);
    }
  }
  for (; e < s1; ++e)
    if (act) accA += lut[zA[(size_t)cs_aa[e] * 192 + t]];
  const float invA = 1.f / fmaxf((float)(s1 - s0), 1.f);
  float* orow = ((h == 0) ? o0 : ((h == 1) ? o1 : o2)) + (size_t)node * Oh + (t - base);
  float v = 0.f;
  if (act) v = *orow + accT * invT + accA * invA;
  if (act) sb[t] = v;
  __syncthreads();
  const int wv = t >> 6, ln = t & 63;
  {
    const int b = (wv == 0) ? 0 : ((wv == 1) ? 129 : 161);
    const int W = (wv == 0) ? 129 : ((wv == 1) ? 32 : 18);
    float m = -3.4e38f;
    for (int i = ln; i < W; i += 64) m = fmaxf(m, sb[b + i]);
    #pragma unroll
    for (int o = 32; o; o >>= 1) m = fmaxf(m, __shfl_xor(m, o));
    float s = 0.f;
    for (int i = ln; i < W; i += 64) s += expf(sb[b + i] - m);
    #pragma unroll
    for (int o = 32; o; o >>= 1) s += __shfl_xor(s, o);
    if (ln == 0) lse[wv] = m + logf(s);
  }
  __syncthreads();
  if (act) *orow = v - lse[h];
}

// ---------------- host ----------------
extern "C" void kernel_launch(void* const* d_in, const int* in_sizes, int n_in,
                              void* d_out, int out_size, void* d_ws, size_t ws_size,
                              hipStream_t stream){
  (void)n_in; (void)out_size; (void)ws_size;
  const float* xa  = (const float*)d_in[0];
  const float* xt  = (const float*)d_in[1];
  const int*   e_at = (const int*)d_in[2];
  const int*   e_ta = (const int*)d_in[3];
  const int*   e_aa = (const int*)d_in[4];
  const float* Wl1 = (const float*)d_in[5];
  const float* Wr1 = (const float*)d_in[6];
  const float* b1  = (const float*)d_in[7];
  const float* Wl2_[3] = {(const float*)d_in[8],  (const float*)d_in[11], (const float*)d_in[14]};
  const float* Wr2_[3] = {(const float*)d_in[9],  (const float*)d_in[12], (const float*)d_in[15]};
  const float* b2_[3]  = {(const float*)d_in[10], (const float*)d_in[13], (const float*)d_in[16]};

  const int NA = in_sizes[0] / 128;
  const int NT = in_sizes[1] / 128;
  const int EAT = in_sizes[2] / 2, ETA = in_sizes[3] / 2, EAA = in_sizes[4] / 2;
  const int Ov[3] = {129, 32, 18};
  const int og[3] = {0, 129, 161};

  // -------- workspace layout (~267 MB) --------
  char* Wp = (char*)d_ws;
  size_t off = 0;
  auto alloc = [&](size_t bytes)->char*{
    char* p = Wp + off; off = (off + bytes + 255) & ~(size_t)255; return p;
  };
  bf16* xa_b = (bf16*)alloc((size_t)NA * 128 * 2);
  bf16* xt_b = (bf16*)alloc((size_t)NT * 128 * 2);
  bf16* m_at = (bf16*)alloc((size_t)NT * 128 * 2);
  bf16* m_ta = (bf16*)alloc((size_t)NA * 128 * 2);
  bf16* m_aa = (bf16*)alloc((size_t)NA * 128 * 2);
  bf16* h_a  = (bf16*)alloc((size_t)NA * 256 * 2);
  bf16* h_t  = (bf16*)alloc((size_t)NT * 256 * 2);
  uint8_t* zA_at = (uint8_t*)alloc((size_t)NA * 192);
  uint8_t* zT_ta = (uint8_t*)alloc((size_t)NT * 192);
  uint8_t* zA_aa = (uint8_t*)alloc((size_t)NA * 192);
  bf16* Bt_ha = (bf16*)alloc((size_t)256 * 384 * 2);
  bf16* Bt_ht = (bf16*)alloc((size_t)256 * 256 * 2);
  bf16* BT2a  = (bf16*)alloc((size_t)3 * 129 * 256 * 2);
  bf16* BT2t  = (bf16*)alloc((size_t)2 * 129 * 256 * 2);
  float* bc1  = (float*)alloc(256 * 4);
  float* bc2  = (float*)alloc(129 * 4);
  int* rs_at  = (int*)alloc((size_t)(NT + 1) * 4);
  int* rs_ta  = (int*)alloc((size_t)(NA + 1) * 4);
  int* rs_aa  = (int*)alloc((size_t)(NA + 1) * 4);
  int* cur_at = (int*)alloc((size_t)NT * 4);
  int* cur_ta = (int*)alloc((size_t)NA * 4);
  int* cur_aa = (int*)alloc((size_t)NA * 4);
  int* bsum   = (int*)alloc(2048 * 4);
  int* cs_at  = (int*)alloc((size_t)EAT * 4);
  int* cs_ta  = (int*)alloc((size_t)ETA * 4);
  int* cs_aa  = (int*)alloc((size_t)EAA * 4);

  // bf16 copies of inputs
  k_f2bf<<<(NA * 128 / 4 + 255) / 256, 256, 0, stream>>>(xa, xa_b, NA * 128 / 4);
  k_f2bf<<<(NT * 128 / 4 + 255) / 256, 256, 0, stream>>>(xt, xt_b, NT * 128 / 4);

  // CSR build (shared by all 3 GNNs)
  auto build_csr = [&](const int* edges, int E, int n, int* rs, int* cur, int* cs){
    int ebl = (E + 255) / 256, nbl = (n + 255) / 256;
    k_zeroi<<<nbl, 256, 0, stream>>>(cur, n);
    k_deg<<<ebl, 256, 0, stream>>>(edges + E, cur, E);
    k_scan_partial<<<nbl, 256, 0, stream>>>(cur, rs, bsum, n);
    k_scan_bsum<<<1, 1024, 0, stream>>>(bsum, nbl, rs + n);
    k_scan_add<<<nbl, 256, 0, stream>>>(rs, bsum, n);
    k_zeroi<<<nbl, 256, 0, stream>>>(cur, n);
    k_fill<<<ebl, 256, 0, stream>>>(edges, edges + E, rs, cur, cs, E);
  };
  build_csr(e_at, EAT, NT, rs_at, cur_at, cs_at);
  build_csr(e_ta, ETA, NA, rs_ta, cur_ta, cs_ta);
  build_csr(e_aa, EAA, NA, rs_aa, cur_aa, cs_aa);

  // layer-1 mean aggregations (g-invariant)
  k_agg128b<<<NT, 64, 0, stream>>>(xa_b, rs_at, cs_at, m_at);
  k_agg128b<<<NA, 64, 0, stream>>>(xt_b, rs_ta, cs_ta, m_ta);
  k_agg128b<<<NA, 64, 0, stream>>>(xa_b, rs_aa, cs_aa, m_aa);

  // d_out head base offsets
  size_t offA[3], offT[3], cum = 0;
  for (int g = 0; g < 3; ++g){
    offA[g] = cum; offT[g] = cum + (size_t)NA * Ov[g];
    cum += (size_t)(NA + NT) * Ov[g];
  }

  for (int g = 0; g < 3; ++g){
    const int O = Ov[g];
    float* outA = (float*)d_out + offA[g];
    float* outT = (float*)d_out + offT[g];
    const float* Wl1g = Wl1 + (size_t)(3 * g) * 128 * 256;
    const float* Wr1g = Wr1 + (size_t)(3 * g) * 128 * 256;
    const float* b1g  = b1  + (size_t)(3 * g) * 256;

    // weight prep (bf16, transposed, combined)
    k_wt1a<<<dim3(3, 256), 128, 0, stream>>>(Wl1g, Wr1g, Bt_ha);
    k_wt1t<<<dim3(2, 256), 128, 0, stream>>>(Wl1g, Wr1g, Bt_ht);
    k_wt2a<<<dim3(2, 3 * O), 128, 0, stream>>>(Wl2_[g], Wr2_[g], O, BT2a);
    k_wt2t<<<dim3(2, 2 * O), 128, 0, stream>>>(Wl2_[g], Wr2_[g], O, BT2t);
    k_bias<<<1, 256, 0, stream>>>(b1g, b2_[g], O, bc1, bc2);

    // dropout keys (threefry scheme verified R2/R3)
    uint32_t kg0, kg1, ka0, ka1, kt0, kt1;
    tf2x32(0u, 42u, 0u, (uint32_t)g, &kg0, &kg1);
    tf2x32(kg0, kg1, 0u, 0u, &ka0, &ka1);
    tf2x32(kg0, kg1, 0u, 1u, &kt0, &kt1);

    // layer 1 (MFMA + fused bias+relu+dropout)
    k_gemm_mfma<0><<<dim3(4, (NA + 127) / 128), 256, 0, stream>>>(
        m_ta, m_aa, xa_b, 128, Bt_ha, 384, NA, 256, 384,
        h_a, nullptr, nullptr, nullptr, bc1, 0, 0, ka0, ka1);
    k_gemm_mfma<0><<<dim3(4, (NT + 127) / 128), 256, 0, stream>>>(
        m_at, xt_b, xt_b, 128, Bt_ht, 256, NT, 256, 256,
        h_t, nullptr, nullptr, nullptr, b1g, 0, 0, kt0, kt1);

    // layer 2: one multi-strip GEMM per source
    k_gemm_mfma<1><<<dim3((3 * O + 63) / 64, (NA + 127) / 128), 256, 0, stream>>>(
        h_a, h_a + 128, h_a, 256, BT2a, 256, NA, 3 * O, 256,
        nullptr, zA_at, zA_aa, outA, bc2, O, og[g], 0, 0);
    k_gemm_mfma<2><<<dim3((2 * O + 63) / 64, (NT + 127) / 128), 256, 0, stream>>>(
        h_t, h_t + 128, h_t, 256, BT2t, 256, NT, 2 * O, 256,
        nullptr, zT_ta, nullptr, outT, b2_[g], O, og[g], 0, 0);
  }

  // fused fp8 gather-mean + log_softmax over all 3 heads
  k_assemble_t<<<NT, 192, 0, stream>>>(zA_at, rs_at, cs_at,
                                       (float*)d_out + offT[0], (float*)d_out + offT[1],
                                       (float*)d_out + offT[2]);
  k_assemble_a<<<NA, 192, 0, stream>>>(zT_ta, zA_aa, rs_ta, cs_ta, rs_aa, cs_aa,
                                       (float*)d_out + offA[0], (float*)d_out + offA[1],
                                       (float*)d_out + offA[2]);
}